// Round 9
// baseline (612.456 us; speedup 1.0000x reference)
//
#include <hip/hip_runtime.h>
#include <math.h>

typedef __attribute__((ext_vector_type(8))) short bf16x8;
typedef __attribute__((ext_vector_type(4))) float f32x4;

namespace {
constexpr int NN = 2048;
constexpr float EPSV = 1e-5f;

// ---- workspace layout (bytes) ----
constexpr size_t WK_O   = 0;        // ushort[256*128]  Wk bf16 [o][c]
constexpr size_t WV_O   = 65536;    // ushort[256*128]  Wv bf16 [o][c]
constexpr size_t WEP_O  = 131072;   // ushort[256*256]  We bf16 [o][c]
constexpr size_t B1F_O  = 262144;   // float[1024]      folded bn bias for layer1
constexpr size_t WIMG_O = 266240;   // 32 pair-chunks x 32KB pre-swizzled [Wa1p 16KB | Wa2p 16KB]
constexpr size_t WP1Q_O = 1314816;  // float[64*4]      folded Wp1@Wq (+bias in .w)
constexpr size_t SC_O   = 1315840;  // float[1024]      attn bn scale

// ---- LDS layout (bytes) ----
constexpr int DBUF_OFF = 0;        // 32KB single-buffered pair-chunk image
constexpr int SCW_OFF  = 32768;    // 4 waves x 1KB: key/X/val slices, then hr
constexpr int PE_OFF   = 36864;    // 4 waves x 1KB (qpe' 512B + pe 512B); with B1L aliased as agg[16][512B]
constexpr int B1L_OFF  = 40960;    // float[1024]
constexpr int LDS_TOTAL = 45056;   // 44KB -> 3 blocks/CU
}

__device__ __forceinline__ unsigned short f2bf(float x) {
    unsigned u = __float_as_uint(x);
    unsigned r = (u + 0x7FFFu + ((u >> 16) & 1u)) >> 16;
    return (unsigned short)r;
}
__device__ __forceinline__ float bf2f(unsigned short h) {
    return __uint_as_float(((unsigned)h) << 16);
}
__device__ __forceinline__ void gl_lds16(const void* gsrc, void* ldst) {
    __builtin_amdgcn_global_load_lds(
        (const __attribute__((address_space(1))) unsigned int*)gsrc,
        (__attribute__((address_space(3))) unsigned int*)ldst,
        16, 0, 0);
}

// ================= prep kernels =================

__global__ void prep_sc(const float* __restrict__ ag,  const float* __restrict__ ab,
                        const float* __restrict__ am,  const float* __restrict__ av,
                        const float* __restrict__ ba1,
                        const float* __restrict__ Wp1, const float* __restrict__ Wq,
                        const float* __restrict__ bq,  const float* __restrict__ bp1,
                        const float* __restrict__ pg,  const float* __restrict__ pb,
                        const float* __restrict__ pm,  const float* __restrict__ pv,
                        char* __restrict__ ws)
{
    const int t = threadIdx.x, blk = blockIdx.x;
    float* b1f  = (float*)(ws + B1F_O);
    float* sc_s = (float*)(ws + SC_O);
    float* wp1q = (float*)(ws + WP1Q_O);
    if (blk < 4) {
        int j = blk * 256 + t;
        float sc = ag[j] * rsqrtf(av[j] + EPSV);
        sc_s[j] = sc;
        b1f[j] = ba1[j] * sc + ab[j] - am[j] * sc;
    } else if (t < 64) {
        int ph = t;
        float scp = pg[ph] * rsqrtf(pv[ph] + EPSV);
        float a0 = 0.f, a1 = 0.f, a2 = 0.f, abv = 0.f;
        for (int c = 0; c < 256; ++c) {
            float wv = Wp1[ph * 256 + c];
            a0 = fmaf(wv, Wq[c * 3 + 0], a0);
            a1 = fmaf(wv, Wq[c * 3 + 1], a1);
            a2 = fmaf(wv, Wq[c * 3 + 2], a2);
            abv = fmaf(wv, bq[c], abv);
        }
        wp1q[ph * 4 + 0] = scp * a0;
        wp1q[ph * 4 + 1] = scp * a1;
        wp1q[ph * 4 + 2] = scp * a2;
        wp1q[ph * 4 + 3] = scp * (abv + bp1[ph]) + (pb[ph] - pm[ph] * scp);
    }
}

// bf16 conversions + pre-swizzled pair-chunk images; 640 blocks x 256
__global__ void prep_cvt(const float* __restrict__ Wk, const float* __restrict__ Wv,
                         const float* __restrict__ We, const float* __restrict__ Wa1,
                         const float* __restrict__ Wa2, char* __restrict__ ws)
{
    const int idx4 = blockIdx.x * 256 + threadIdx.x;
    if (idx4 >= 163840) return;
    const int e0 = idx4 * 4;
    const float* sc_s = (const float*)(ws + SC_O);

    if (e0 < 131072) {   // Wk | Wv | We linear bf16
        const float* src;
        unsigned short* dst;
        if (e0 < 32768)      { src = Wk + e0;          dst = (unsigned short*)(ws + WK_O)  + e0; }
        else if (e0 < 65536) { int e = e0 - 32768; src = Wv + e; dst = (unsigned short*)(ws + WV_O)  + e; }
        else                 { int e = e0 - 65536; src = We + e; dst = (unsigned short*)(ws + WEP_O) + e; }
        float4 v = *(const float4*)src;
        ushort4 o;
        o.x = f2bf(v.x); o.y = f2bf(v.y); o.z = f2bf(v.z); o.w = f2bf(v.w);
        *(ushort4*)dst = o;
    } else if (e0 < 393216) {   // Wa1 folded -> pair image [32j][256c] swz ^((jl&7)<<4)
        int e = e0 - 131072;
        int j = e >> 8, c = e & 255;
        float sc = sc_s[j];
        float4 v = *(const float4*)(Wa1 + e);
        int p = j >> 5, jl = j & 31;
        size_t byte = (size_t)p * 32768 + ((jl * 512 + c * 2) ^ ((jl & 7) << 4));
        ushort4 o;
        o.x = f2bf(v.x * sc); o.y = f2bf(v.y * sc); o.z = f2bf(v.z * sc); o.w = f2bf(v.w * sc);
        *(ushort4*)(ws + WIMG_O + byte) = o;
    } else {                    // Wa2 -> pair image, o-pair rows of 128B, swz ^(((o>>1)&7)<<4)
        int e = e0 - 393216;
        int o = e >> 10, j = e & 1023;
        float4 v = *(const float4*)(Wa2 + e);
        int p = j >> 5, jj = j & 31;
        size_t byte = (size_t)p * 32768 + 16384 +
                      (((o >> 1) * 128 + (o & 1) * 64 + jj * 2) ^ (((o >> 1) & 7) << 4));
        ushort4 ov;
        ov.x = f2bf(v.x); ov.y = f2bf(v.y); ov.z = f2bf(v.z); ov.w = f2bf(v.w);
        *(ushort4*)(ws + WIMG_O + byte) = ov;
    }
}

// ================= main fused kernel =================
// 2048 blocks (4 b x 512 n-tiles of 4), 256 threads = 4 waves; wave owns ONE n
// (16 MFMA rows = 16 k). Loop live set ~110-135 VGPR (Y[16]=64 + ax[8]=32 + temps)
// so even the allocator's stubborn 128-170 choices are spill-free (rounds 4-8:
// 2-n waves needed ~235 regs -> ~1GB scratch WRITE_SIZE regardless of attributes).
__global__ __launch_bounds__(256, 3)
void pt_main(const float* __restrict__ key, const float* __restrict__ values,
             const float* __restrict__ pos,
             const float* __restrict__ Wq,  const float* __restrict__ bq,
             const float* __restrict__ bk,  const float* __restrict__ bv,
             const float* __restrict__ Wp2, const float* __restrict__ bp2,
             const float* __restrict__ be,
             const char* __restrict__ ws,
             float* __restrict__ outp)
{
    extern __shared__ char sm[];
    const int t = threadIdx.x;
    const int w = t >> 6, l = t & 63;
    const int l15 = l & 15, lg = l >> 4;
    // XCD-aware swizzle (2048 % 8 == 0 -> bijective)
    const int wg = (blockIdx.x & 7) * 256 + (blockIdx.x >> 3);
    const int b = wg >> 9;
    const int n0 = (wg & 511) * 4;
    const int n = n0 + w;            // this wave's n

    char* scw = sm + SCW_OFF + w * 1024;
    char* pew = sm + PE_OFF + w * 1024;
    float* b1l = (float*)(sm + B1L_OFF);

    const unsigned short* wkp = (const unsigned short*)(ws + WK_O);
    const unsigned short* wvp = (const unsigned short*)(ws + WV_O);
    const unsigned short* wep = (const unsigned short*)(ws + WEP_O);
    const float* b1fp = (const float*)(ws + B1F_O);
    const float* wp1q = (const float*)(ws + WP1Q_O);
    const char* wimg = ws + WIMG_O;

    const f32x4 zf = {0.f, 0.f, 0.f, 0.f};

    // ---- prologue: stage pair-chunk 0 (lands during the pre-phase) ----
    #pragma unroll
    for (int i = 0; i < 8; ++i)
        gl_lds16(wimg + i * 4096 + t * 16, sm + DBUF_OFF + i * 4096 + t * 16);

    // ---- b1f -> LDS ----
    #pragma unroll
    for (int i = 0; i < 4; ++i) b1l[t + i * 256] = b1fp[t + i * 256];

    // ---- pe / qpe' phase (wave-local, 1 n) ----
    float p0, p1, p2;
    {
        const float4 wq4 = *(const float4*)(wp1q + l * 4);
        p0 = pos[(b * 3 + 0) * NN + n];
        p1 = pos[(b * 3 + 1) * NN + n];
        p2 = pos[(b * 3 + 2) * NN + n];
        float h1v = fmaxf(fmaf(wq4.x, p0, fmaf(wq4.y, p1, fmaf(wq4.z, p2, wq4.w))), 0.f);
        float pacc[4];
        #pragma unroll
        for (int oi = 0; oi < 4; ++oi) pacc[oi] = 0.f;
        #pragma unroll 4
        for (int j4 = 0; j4 < 16; ++j4) {
            float h[4];
            #pragma unroll
            for (int jj = 0; jj < 4; ++jj) h[jj] = __shfl(h1v, j4 * 4 + jj);
            #pragma unroll
            for (int oi = 0; oi < 4; ++oi) {
                const float4 wv4 = *(const float4*)(Wp2 + (oi * 64 + l) * 64 + j4 * 4);
                pacc[oi] = fmaf(wv4.x, h[0], fmaf(wv4.y, h[1], fmaf(wv4.z, h[2], fmaf(wv4.w, h[3], pacc[oi]))));
            }
        }
        #pragma unroll
        for (int oi = 0; oi < 4; ++oi) {
            int o = oi * 64 + l;
            float pe = pacc[oi] + bp2[o];
            float q  = fmaf(Wq[o * 3 + 0], p0, fmaf(Wq[o * 3 + 1], p1, fmaf(Wq[o * 3 + 2], p2, bq[o])));
            *(unsigned short*)(pew + o * 2)       = f2bf((q + 1.f - bk[o]) * pe);
            *(unsigned short*)(pew + 512 + o * 2) = f2bf(pe);
        }
    }

    // ---- kf GEMM in 4 c-slices of 32 through 1KB wave-private scratch ----
    // slice layout [16m][32c] bf16, pair-rows of 128B, swz ^(((m>>1)&7)<<4)
    const int kq = l & 3, cL = l >> 2;
    f32x4 kacc[16];
    #pragma unroll
    for (int ot = 0; ot < 16; ++ot) kacc[ot] = zf;

    #pragma unroll 1
    for (int s = 0; s < 4; ++s) {
        const float* kb = key + ((size_t)b * 128 * NN + n) * 16 + kq * 4;
        #pragma unroll
        for (int h = 0; h < 2; ++h) {
            int c = s * 32 + h * 16 + cL;
            float4 v = *(const float4*)(kb + (size_t)c * NN * 16);
            int cl = h * 16 + cL;
            #pragma unroll
            for (int j = 0; j < 4; ++j) {
                int m = kq * 4 + j;
                float fj = (j == 0) ? v.x : (j == 1) ? v.y : (j == 2) ? v.z : v.w;
                *(unsigned short*)(scw + (((m >> 1) * 128 + (m & 1) * 64 + cl * 2) ^ (((m >> 1) & 7) << 4))) = f2bf(fj);
            }
        }
        bf16x8 kB = *(const bf16x8*)(scw + (((l15 >> 1) * 128 + (l15 & 1) * 64 + lg * 16) ^ (((l15 >> 1) & 7) << 4)));
        #pragma unroll 4
        for (int ot = 0; ot < 16; ++ot) {
            bf16x8 aW = *(const bf16x8*)(wkp + (ot * 16 + l15) * 128 + s * 32 + lg * 8);
            kacc[ot] = __builtin_amdgcn_mfma_f32_16x16x32_bf16(aW, kB, kacc[ot], 0, 0, 0);
        }
    }

    // ---- X epilogue -> ax registers, 8 o-slices of 32 through scratch ----
    bf16x8 ax[8];
    #pragma unroll 1
    for (int x = 0; x < 8; ++x) {
        #pragma unroll
        for (int oi = 0; oi < 2; ++oi) {
            int ot = x * 2 + oi;
            int o0 = ot * 16 + lg * 4;
            ushort4 qv  = *(const ushort4*)(pew + o0 * 2);
            ushort4 pv4 = *(const ushort4*)(pew + 512 + o0 * 2);
            ushort4 pk;
            pk.x = f2bf(bf2f(qv.x) - kacc[ot][0] * bf2f(pv4.x));
            pk.y = f2bf(bf2f(qv.y) - kacc[ot][1] * bf2f(pv4.y));
            pk.z = f2bf(bf2f(qv.z) - kacc[ot][2] * bf2f(pv4.z));
            pk.w = f2bf(bf2f(qv.w) - kacc[ot][3] * bf2f(pv4.w));
            int ol = oi * 16 + lg * 4;
            *(ushort4*)(scw + (((l15 >> 1) * 128 + (l15 & 1) * 64 + ol * 2) ^ (((l15 >> 1) & 7) << 4))) = pk;
        }
        ax[x] = *(const bf16x8*)(scw + (((l15 >> 1) * 128 + (l15 & 1) * 64 + lg * 16) ^ (((l15 >> 1) & 7) << 4)));
    }

    // ---- attn MLP: 32 pair-chunks of 32 j; single-buffered gl_lds image staging ----
    f32x4 Y[16];
    #pragma unroll
    for (int ot = 0; ot < 16; ++ot) Y[ot] = zf;

    char* hrb = scw;  // wave-private hr [16m][32j] bf16, pair-rows 128B, swz

    #pragma unroll 1
    for (int p = 0; p < 32; ++p) {
        asm volatile("s_waitcnt vmcnt(0) lgkmcnt(0)" ::: "memory");
        __builtin_amdgcn_s_barrier();          // image p ready for all waves
        __builtin_amdgcn_sched_barrier(0);

        // layer1: C[j][m] = Wa1p @ X   (A = Wa1 rows j, B = ax cols m)
        __builtin_amdgcn_s_setprio(1);
        #pragma unroll
        for (int jt = 0; jt < 2; ++jt) {
            const int jl = jt * 16 + l15;
            f32x4 c1 = zf;
            #pragma unroll
            for (int kt = 0; kt < 8; ++kt) {
                bf16x8 aw1 = *(const bf16x8*)(sm + DBUF_OFF + jl * 512 + ((kt * 64 + lg * 16) ^ ((jl & 7) << 4)));
                c1 = __builtin_amdgcn_mfma_f32_16x16x32_bf16(aw1, ax[kt], c1, 0, 0, 0);
            }
            // bias+relu; lane holds 4 consecutive j for col m=l15 -> packed b64 write
            const float4 b4 = *(const float4*)(b1l + p * 32 + jt * 16 + lg * 4);
            ushort4 hw;
            hw.x = f2bf(fmaxf(c1[0] + b4.x, 0.f));
            hw.y = f2bf(fmaxf(c1[1] + b4.y, 0.f));
            hw.z = f2bf(fmaxf(c1[2] + b4.z, 0.f));
            hw.w = f2bf(fmaxf(c1[3] + b4.w, 0.f));
            int jb = (jt * 16 + lg * 4) * 2;
            *(ushort4*)(hrb + (((l15 >> 1) * 128 + (l15 & 1) * 64 + jb) ^ (((l15 >> 1) & 7) << 4))) = hw;
        }
        // layer2: Y += hr @ Wa2p^T (A = hr rows m(=k), B = Wa2 cols o), K = 32
        bf16x8 ah = *(const bf16x8*)(hrb + (((l15 >> 1) * 128 + (l15 & 1) * 64 + lg * 16) ^ (((l15 >> 1) & 7) << 4)));
        #pragma unroll
        for (int ot = 0; ot < 16; ++ot) {
            int o = ot * 16 + l15;
            bf16x8 bW2 = *(const bf16x8*)(sm + DBUF_OFF + 16384 +
                          (((o >> 1) * 128 + (o & 1) * 64 + lg * 16) ^ (((o >> 1) & 7) << 4)));
            Y[ot] = __builtin_amdgcn_mfma_f32_16x16x32_bf16(ah, bW2, Y[ot], 0, 0, 0);
        }
        __builtin_amdgcn_s_setprio(0);

        asm volatile("s_waitcnt lgkmcnt(0)" ::: "memory");
        __builtin_amdgcn_s_barrier();          // all waves done reading image p
        if (p < 31) {
            const char* src = wimg + (size_t)(p + 1) * 32768;
            #pragma unroll
            for (int i = 0; i < 8; ++i)
                gl_lds16(src + i * 4096 + t * 16, sm + DBUF_OFF + i * 4096 + t * 16);
        }
    }

    // ---- softmax over k (k = lg*4+r; registers + shfl) ----
    #pragma unroll
    for (int ot = 0; ot < 16; ++ot) {
        float mx = fmaxf(fmaxf(Y[ot][0], Y[ot][1]), fmaxf(Y[ot][2], Y[ot][3]));
        mx = fmaxf(mx, __shfl_xor(mx, 16));
        mx = fmaxf(mx, __shfl_xor(mx, 32));
        float e0 = expf(Y[ot][0] - mx), e1 = expf(Y[ot][1] - mx);
        float e2 = expf(Y[ot][2] - mx), e3 = expf(Y[ot][3] - mx);
        float s = e0 + e1 + e2 + e3;
        s += __shfl_xor(s, 16);
        s += __shfl_xor(s, 32);
        float inv = 1.f / s;
        Y[ot][0] = e0 * inv; Y[ot][1] = e1 * inv;
        Y[ot][2] = e2 * inv; Y[ot][3] = e3 * inv;
    }

    // ---- values -> vB regs via 4 slices; then v GEMM + agg ----
    bf16x8 vB[4];
    #pragma unroll 1
    for (int s = 0; s < 4; ++s) {
        const float* vb = values + ((size_t)b * 128 * NN + n) * 16 + kq * 4;
        #pragma unroll
        for (int h = 0; h < 2; ++h) {
            int c = s * 32 + h * 16 + cL;
            float4 v = *(const float4*)(vb + (size_t)c * NN * 16);
            int cl = h * 16 + cL;
            #pragma unroll
            for (int j = 0; j < 4; ++j) {
                int m = kq * 4 + j;
                float fj = (j == 0) ? v.x : (j == 1) ? v.y : (j == 2) ? v.z : v.w;
                *(unsigned short*)(scw + (((m >> 1) * 128 + (m & 1) * 64 + cl * 2) ^ (((m >> 1) & 7) << 4))) = f2bf(fj);
            }
        }
        vB[s] = *(const bf16x8*)(scw + (((l15 >> 1) * 128 + (l15 & 1) * 64 + lg * 16) ^ (((l15 >> 1) & 7) << 4)));
    }

    float aggv[16];
    #pragma unroll 4
    for (int ot = 0; ot < 16; ++ot) {
        int o = ot * 16 + l15;
        f32x4 va = zf;
        #pragma unroll
        for (int s = 0; s < 4; ++s) {
            bf16x8 bWv = *(const bf16x8*)(wvp + o * 128 + s * 32 + lg * 8);
            va = __builtin_amdgcn_mfma_f32_16x16x32_bf16(vB[s], bWv, va, 0, 0, 0);
        }
        float bvo = bv[o];
        float s = Y[ot][0] * (va[0] + bvo);
        s = fmaf(Y[ot][1], va[1] + bvo, s);
        s = fmaf(Y[ot][2], va[2] + bvo, s);
        s = fmaf(Y[ot][3], va[3] + bvo, s);
        s += __shfl_xor(s, 16);
        s += __shfl_xor(s, 32);
        aggv[ot] = s + bf2f(*(const unsigned short*)(pew + 512 + o * 2));
    }

    __syncthreads();
    // ---- agg hand-off: agg[16rows][256o] bf16 aliasing (pew+b1l) 8KB; row w = this n ----
    if (lg == 0) {
        #pragma unroll
        for (int ot = 0; ot < 16; ++ot) {
            int o = ot * 16 + l15;
            *(unsigned short*)(sm + PE_OFF + ((w * 512 + o * 2) ^ ((w & 7) << 4))) = f2bf(aggv[ot]);
        }
    }
    __syncthreads();

    // ---- We GEMM: wave owns 64 oo; A rows l15 (4 real n, rest garbage -> discarded) ----
    bf16x8 aa[8];
    #pragma unroll
    for (int kt = 0; kt < 8; ++kt)
        aa[kt] = *(const bf16x8*)(sm + PE_OFF + ((l15 * 512 + kt * 64 + lg * 16) ^ ((l15 & 7) << 4)));
    #pragma unroll
    for (int ot = 0; ot < 4; ++ot) {
        int oo = w * 64 + ot * 16 + l15;
        f32x4 acc = zf;
        #pragma unroll
        for (int kt = 0; kt < 8; ++kt) {
            bf16x8 bWe = *(const bf16x8*)(wep + oo * 256 + kt * 32 + lg * 8);
            acc = __builtin_amdgcn_mfma_f32_16x16x32_bf16(aa[kt], bWe, acc, 0, 0, 0);
        }
        if (lg == 0) {   // C rows lg*4+r = n0+r, valid rows 0..3
            float bev = be[oo];
            float4 vv;
            vv.x = acc[0] + bev; vv.y = acc[1] + bev;
            vv.z = acc[2] + bev; vv.w = acc[3] + bev;
            *(float4*)(outp + ((size_t)(b * 256 + oo)) * NN + n0) = vv;
        }
    }
}

extern "C" void kernel_launch(void* const* d_in, const int* in_sizes, int n_in,
                              void* d_out, int out_size, void* d_ws, size_t ws_size,
                              hipStream_t stream) {
    const float* key    = (const float*)d_in[0];
    const float* values = (const float*)d_in[1];
    const float* pos    = (const float*)d_in[2];
    const float* Wk     = (const float*)d_in[3];
    const float* bk     = (const float*)d_in[4];
    const float* Wq     = (const float*)d_in[5];
    const float* bq     = (const float*)d_in[6];
    const float* Wv     = (const float*)d_in[7];
    const float* bv     = (const float*)d_in[8];
    const float* Wp1    = (const float*)d_in[9];
    const float* bp1    = (const float*)d_in[10];
    const float* pg     = (const float*)d_in[11];
    const float* pb     = (const float*)d_in[12];
    const float* pm     = (const float*)d_in[13];
    const float* pv     = (const float*)d_in[14];
    const float* Wp2    = (const float*)d_in[15];
    const float* bp2    = (const float*)d_in[16];
    const float* Wa1    = (const float*)d_in[17];
    const float* ba1    = (const float*)d_in[18];
    const float* ag     = (const float*)d_in[19];
    const float* ab     = (const float*)d_in[20];
    const float* am     = (const float*)d_in[21];
    const float* av     = (const float*)d_in[22];
    const float* Wa2    = (const float*)d_in[23];
    const float* We     = (const float*)d_in[25];
    const float* be     = (const float*)d_in[26];
    (void)in_sizes; (void)n_in; (void)out_size; (void)ws_size;

    char* ws = (char*)d_ws;

    hipFuncSetAttribute((const void*)pt_main,
                        hipFuncAttributeMaxDynamicSharedMemorySize, LDS_TOTAL);

    hipLaunchKernelGGL(prep_sc, dim3(5), dim3(256), 0, stream,
                       ag, ab, am, av, ba1, Wp1, Wq, bq, bp1, pg, pb, pm, pv, ws);
    hipLaunchKernelGGL(prep_cvt, dim3(640), dim3(256), 0, stream,
                       Wk, Wv, We, Wa1, Wa2, ws);
    hipLaunchKernelGGL(pt_main, dim3(2048), dim3(256), LDS_TOTAL, stream,
                       key, values, pos, Wq, bq, bk, bv, Wp2, bp2, be,
                       (const char*)ws, (float*)d_out);
}

// Round 10
// 605.617 us; speedup vs baseline: 1.0113x; 1.0113x over previous
//
#include <hip/hip_runtime.h>
#include <math.h>

typedef __attribute__((ext_vector_type(8))) short bf16x8;
typedef __attribute__((ext_vector_type(4))) float f32x4;

namespace {
constexpr int NN = 2048;
constexpr float EPSV = 1e-5f;

// ---- workspace layout (bytes) ----
constexpr size_t WK_O   = 0;        // ushort[256*128]  Wk bf16 [o][c]
constexpr size_t WV_O   = 65536;    // ushort[256*128]  Wv bf16 [o][c]
constexpr size_t WEP_O  = 131072;   // ushort[256*256]  We bf16 [o][c]
constexpr size_t B1F_O  = 262144;   // float[1024]      folded bn bias for layer1
constexpr size_t WIMG_O = 266240;   // 32 pair-chunks x 32KB pre-swizzled [Wa1p 16KB | Wa2p 16KB]
constexpr size_t WP1Q_O = 1314816;  // float[64*4]      folded Wp1@Wq (+bias in .w)
constexpr size_t SC_O   = 1315840;  // float[1024]      attn bn scale

// ---- LDS layout (bytes) ----
constexpr int DBUF_OFF = 0;        // 32KB single-buffered pair-chunk image
constexpr int SCW_OFF  = 32768;    // 4 waves x 1KB: key/X/val slices, then hr
constexpr int PE_OFF   = 36864;    // 4 waves x 1KB (qpe' 512B + pe 512B); +B1L aliased as agg region
constexpr int B1L_OFF  = 40960;    // float[1024]
constexpr int LDS_TOTAL = 45056;   // 44KB STATIC -> compiler sees 3 blocks/CU max ->
                                   // occupancy target 3 waves/EU -> ~170 VGPR budget.
                                   // (dynamic extern __shared__ hid LDS from the register
                                   //  allocator; it targeted 6+ waves/EU and spilled ~1GB --
                                   //  rounds 4-9 WRITE_SIZE evidence)
}

__device__ __forceinline__ unsigned short f2bf(float x) {
    unsigned u = __float_as_uint(x);
    unsigned r = (u + 0x7FFFu + ((u >> 16) & 1u)) >> 16;
    return (unsigned short)r;
}
__device__ __forceinline__ float bf2f(unsigned short h) {
    return __uint_as_float(((unsigned)h) << 16);
}
__device__ __forceinline__ void gl_lds16(const void* gsrc, void* ldst) {
    __builtin_amdgcn_global_load_lds(
        (const __attribute__((address_space(1))) unsigned int*)gsrc,
        (__attribute__((address_space(3))) unsigned int*)ldst,
        16, 0, 0);
}

// ================= prep kernels =================

__global__ void prep_sc(const float* __restrict__ ag,  const float* __restrict__ ab,
                        const float* __restrict__ am,  const float* __restrict__ av,
                        const float* __restrict__ ba1,
                        const float* __restrict__ Wp1, const float* __restrict__ Wq,
                        const float* __restrict__ bq,  const float* __restrict__ bp1,
                        const float* __restrict__ pg,  const float* __restrict__ pb,
                        const float* __restrict__ pm,  const float* __restrict__ pv,
                        char* __restrict__ ws)
{
    const int t = threadIdx.x, blk = blockIdx.x;
    float* b1f  = (float*)(ws + B1F_O);
    float* sc_s = (float*)(ws + SC_O);
    float* wp1q = (float*)(ws + WP1Q_O);
    if (blk < 4) {
        int j = blk * 256 + t;
        float sc = ag[j] * rsqrtf(av[j] + EPSV);
        sc_s[j] = sc;
        b1f[j] = ba1[j] * sc + ab[j] - am[j] * sc;
    } else if (t < 64) {
        int ph = t;
        float scp = pg[ph] * rsqrtf(pv[ph] + EPSV);
        float a0 = 0.f, a1 = 0.f, a2 = 0.f, abv = 0.f;
        for (int c = 0; c < 256; ++c) {
            float wv = Wp1[ph * 256 + c];
            a0 = fmaf(wv, Wq[c * 3 + 0], a0);
            a1 = fmaf(wv, Wq[c * 3 + 1], a1);
            a2 = fmaf(wv, Wq[c * 3 + 2], a2);
            abv = fmaf(wv, bq[c], abv);
        }
        wp1q[ph * 4 + 0] = scp * a0;
        wp1q[ph * 4 + 1] = scp * a1;
        wp1q[ph * 4 + 2] = scp * a2;
        wp1q[ph * 4 + 3] = scp * (abv + bp1[ph]) + (pb[ph] - pm[ph] * scp);
    }
}

// bf16 conversions + pre-swizzled pair-chunk images; 640 blocks x 256
__global__ void prep_cvt(const float* __restrict__ Wk, const float* __restrict__ Wv,
                         const float* __restrict__ We, const float* __restrict__ Wa1,
                         const float* __restrict__ Wa2, char* __restrict__ ws)
{
    const int idx4 = blockIdx.x * 256 + threadIdx.x;
    if (idx4 >= 163840) return;
    const int e0 = idx4 * 4;
    const float* sc_s = (const float*)(ws + SC_O);

    if (e0 < 131072) {   // Wk | Wv | We linear bf16
        const float* src;
        unsigned short* dst;
        if (e0 < 32768)      { src = Wk + e0;          dst = (unsigned short*)(ws + WK_O)  + e0; }
        else if (e0 < 65536) { int e = e0 - 32768; src = Wv + e; dst = (unsigned short*)(ws + WV_O)  + e; }
        else                 { int e = e0 - 65536; src = We + e; dst = (unsigned short*)(ws + WEP_O) + e; }
        float4 v = *(const float4*)src;
        ushort4 o;
        o.x = f2bf(v.x); o.y = f2bf(v.y); o.z = f2bf(v.z); o.w = f2bf(v.w);
        *(ushort4*)dst = o;
    } else if (e0 < 393216) {   // Wa1 folded -> pair image [32j][256c] swz ^((jl&7)<<4)
        int e = e0 - 131072;
        int j = e >> 8, c = e & 255;
        float sc = sc_s[j];
        float4 v = *(const float4*)(Wa1 + e);
        int p = j >> 5, jl = j & 31;
        size_t byte = (size_t)p * 32768 + ((jl * 512 + c * 2) ^ ((jl & 7) << 4));
        ushort4 o;
        o.x = f2bf(v.x * sc); o.y = f2bf(v.y * sc); o.z = f2bf(v.z * sc); o.w = f2bf(v.w * sc);
        *(ushort4*)(ws + WIMG_O + byte) = o;
    } else {                    // Wa2 -> pair image, o-pair rows of 128B, swz ^(((o>>1)&7)<<4)
        int e = e0 - 393216;
        int o = e >> 10, j = e & 1023;
        float4 v = *(const float4*)(Wa2 + e);
        int p = j >> 5, jj = j & 31;
        size_t byte = (size_t)p * 32768 + 16384 +
                      (((o >> 1) * 128 + (o & 1) * 64 + jj * 2) ^ (((o >> 1) & 7) << 4));
        ushort4 ov;
        ov.x = f2bf(v.x); ov.y = f2bf(v.y); ov.z = f2bf(v.z); ov.w = f2bf(v.w);
        *(ushort4*)(ws + WIMG_O + byte) = ov;
    }
}

// ================= main fused kernel =================
// 2048 blocks (4 b x 512 n-tiles of 4), 256 threads = 4 waves; wave owns ONE n
// (16 MFMA rows = 16 k). Loop live set ~110-135 VGPR; static 44KB LDS caps the
// allocator's occupancy target at 3 waves/EU -> ~170 VGPR budget -> no spill.
__global__ __launch_bounds__(256, 3)
void pt_main(const float* __restrict__ key, const float* __restrict__ values,
             const float* __restrict__ pos,
             const float* __restrict__ Wq,  const float* __restrict__ bq,
             const float* __restrict__ bk,  const float* __restrict__ bv,
             const float* __restrict__ Wp2, const float* __restrict__ bp2,
             const float* __restrict__ be,
             const char* __restrict__ ws,
             float* __restrict__ outp)
{
    __shared__ __align__(16) char sm[LDS_TOTAL];
    const int t = threadIdx.x;
    const int w = t >> 6, l = t & 63;
    const int l15 = l & 15, lg = l >> 4;
    // XCD-aware swizzle (2048 % 8 == 0 -> bijective)
    const int wg = (blockIdx.x & 7) * 256 + (blockIdx.x >> 3);
    const int b = wg >> 9;
    const int n0 = (wg & 511) * 4;
    const int n = n0 + w;            // this wave's n

    char* scw = sm + SCW_OFF + w * 1024;
    char* pew = sm + PE_OFF + w * 1024;
    float* b1l = (float*)(sm + B1L_OFF);

    const unsigned short* wkp = (const unsigned short*)(ws + WK_O);
    const unsigned short* wvp = (const unsigned short*)(ws + WV_O);
    const unsigned short* wep = (const unsigned short*)(ws + WEP_O);
    const float* b1fp = (const float*)(ws + B1F_O);
    const float* wp1q = (const float*)(ws + WP1Q_O);
    const char* wimg = ws + WIMG_O;

    const f32x4 zf = {0.f, 0.f, 0.f, 0.f};

    // ---- prologue: stage pair-chunk 0 (lands during the pre-phase) ----
    #pragma unroll
    for (int i = 0; i < 8; ++i)
        gl_lds16(wimg + i * 4096 + t * 16, sm + DBUF_OFF + i * 4096 + t * 16);

    // ---- b1f -> LDS ----
    #pragma unroll
    for (int i = 0; i < 4; ++i) b1l[t + i * 256] = b1fp[t + i * 256];

    // ---- pe / qpe' phase (wave-local, 1 n) ----
    float p0, p1, p2;
    {
        const float4 wq4 = *(const float4*)(wp1q + l * 4);
        p0 = pos[(b * 3 + 0) * NN + n];
        p1 = pos[(b * 3 + 1) * NN + n];
        p2 = pos[(b * 3 + 2) * NN + n];
        float h1v = fmaxf(fmaf(wq4.x, p0, fmaf(wq4.y, p1, fmaf(wq4.z, p2, wq4.w))), 0.f);
        float pacc[4];
        #pragma unroll
        for (int oi = 0; oi < 4; ++oi) pacc[oi] = 0.f;
        #pragma unroll 4
        for (int j4 = 0; j4 < 16; ++j4) {
            float h[4];
            #pragma unroll
            for (int jj = 0; jj < 4; ++jj) h[jj] = __shfl(h1v, j4 * 4 + jj);
            #pragma unroll
            for (int oi = 0; oi < 4; ++oi) {
                const float4 wv4 = *(const float4*)(Wp2 + (oi * 64 + l) * 64 + j4 * 4);
                pacc[oi] = fmaf(wv4.x, h[0], fmaf(wv4.y, h[1], fmaf(wv4.z, h[2], fmaf(wv4.w, h[3], pacc[oi]))));
            }
        }
        #pragma unroll
        for (int oi = 0; oi < 4; ++oi) {
            int o = oi * 64 + l;
            float pe = pacc[oi] + bp2[o];
            float q  = fmaf(Wq[o * 3 + 0], p0, fmaf(Wq[o * 3 + 1], p1, fmaf(Wq[o * 3 + 2], p2, bq[o])));
            *(unsigned short*)(pew + o * 2)       = f2bf((q + 1.f - bk[o]) * pe);
            *(unsigned short*)(pew + 512 + o * 2) = f2bf(pe);
        }
    }

    // ---- kf GEMM in 4 c-slices of 32 through 1KB wave-private scratch ----
    // slice layout [16m][32c] bf16, pair-rows of 128B, swz ^(((m>>1)&7)<<4)
    const int kq = l & 3, cL = l >> 2;
    f32x4 kacc[16];
    #pragma unroll
    for (int ot = 0; ot < 16; ++ot) kacc[ot] = zf;

    #pragma unroll 1
    for (int s = 0; s < 4; ++s) {
        const float* kb = key + ((size_t)b * 128 * NN + n) * 16 + kq * 4;
        #pragma unroll
        for (int h = 0; h < 2; ++h) {
            int c = s * 32 + h * 16 + cL;
            float4 v = *(const float4*)(kb + (size_t)c * NN * 16);
            int cl = h * 16 + cL;
            #pragma unroll
            for (int j = 0; j < 4; ++j) {
                int m = kq * 4 + j;
                float fj = (j == 0) ? v.x : (j == 1) ? v.y : (j == 2) ? v.z : v.w;
                *(unsigned short*)(scw + (((m >> 1) * 128 + (m & 1) * 64 + cl * 2) ^ (((m >> 1) & 7) << 4))) = f2bf(fj);
            }
        }
        bf16x8 kB = *(const bf16x8*)(scw + (((l15 >> 1) * 128 + (l15 & 1) * 64 + lg * 16) ^ (((l15 >> 1) & 7) << 4)));
        #pragma unroll 4
        for (int ot = 0; ot < 16; ++ot) {
            bf16x8 aW = *(const bf16x8*)(wkp + (ot * 16 + l15) * 128 + s * 32 + lg * 8);
            kacc[ot] = __builtin_amdgcn_mfma_f32_16x16x32_bf16(aW, kB, kacc[ot], 0, 0, 0);
        }
    }

    // ---- X epilogue -> ax registers, 8 o-slices of 32 through scratch ----
    bf16x8 ax[8];
    #pragma unroll 1
    for (int x = 0; x < 8; ++x) {
        #pragma unroll
        for (int oi = 0; oi < 2; ++oi) {
            int ot = x * 2 + oi;
            int o0 = ot * 16 + lg * 4;
            ushort4 qv  = *(const ushort4*)(pew + o0 * 2);
            ushort4 pv4 = *(const ushort4*)(pew + 512 + o0 * 2);
            ushort4 pk;
            pk.x = f2bf(bf2f(qv.x) - kacc[ot][0] * bf2f(pv4.x));
            pk.y = f2bf(bf2f(qv.y) - kacc[ot][1] * bf2f(pv4.y));
            pk.z = f2bf(bf2f(qv.z) - kacc[ot][2] * bf2f(pv4.z));
            pk.w = f2bf(bf2f(qv.w) - kacc[ot][3] * bf2f(pv4.w));
            int ol = oi * 16 + lg * 4;
            *(ushort4*)(scw + (((l15 >> 1) * 128 + (l15 & 1) * 64 + ol * 2) ^ (((l15 >> 1) & 7) << 4))) = pk;
        }
        ax[x] = *(const bf16x8*)(scw + (((l15 >> 1) * 128 + (l15 & 1) * 64 + lg * 16) ^ (((l15 >> 1) & 7) << 4)));
    }

    // ---- attn MLP: 32 pair-chunks of 32 j; single-buffered gl_lds image staging ----
    f32x4 Y[16];
    #pragma unroll
    for (int ot = 0; ot < 16; ++ot) Y[ot] = zf;

    char* hrb = scw;  // wave-private hr [16m][32j] bf16, pair-rows 128B, swz

    #pragma unroll 1
    for (int p = 0; p < 32; ++p) {
        asm volatile("s_waitcnt vmcnt(0) lgkmcnt(0)" ::: "memory");
        __builtin_amdgcn_s_barrier();          // image p ready for all waves
        __builtin_amdgcn_sched_barrier(0);

        // layer1: C[j][m] = Wa1p @ X   (A = Wa1 rows j, B = ax cols m)
        __builtin_amdgcn_s_setprio(1);
        #pragma unroll
        for (int jt = 0; jt < 2; ++jt) {
            const int jl = jt * 16 + l15;
            f32x4 c1 = zf;
            #pragma unroll
            for (int kt = 0; kt < 8; ++kt) {
                bf16x8 aw1 = *(const bf16x8*)(sm + DBUF_OFF + jl * 512 + ((kt * 64 + lg * 16) ^ ((jl & 7) << 4)));
                c1 = __builtin_amdgcn_mfma_f32_16x16x32_bf16(aw1, ax[kt], c1, 0, 0, 0);
            }
            // bias+relu; lane holds 4 consecutive j for col m=l15 -> packed b64 write
            const float4 b4 = *(const float4*)(b1l + p * 32 + jt * 16 + lg * 4);
            ushort4 hw;
            hw.x = f2bf(fmaxf(c1[0] + b4.x, 0.f));
            hw.y = f2bf(fmaxf(c1[1] + b4.y, 0.f));
            hw.z = f2bf(fmaxf(c1[2] + b4.z, 0.f));
            hw.w = f2bf(fmaxf(c1[3] + b4.w, 0.f));
            int jb = (jt * 16 + lg * 4) * 2;
            *(ushort4*)(hrb + (((l15 >> 1) * 128 + (l15 & 1) * 64 + jb) ^ (((l15 >> 1) & 7) << 4))) = hw;
        }
        // layer2: Y += hr @ Wa2p^T (A = hr rows m(=k), B = Wa2 cols o), K = 32
        bf16x8 ah = *(const bf16x8*)(hrb + (((l15 >> 1) * 128 + (l15 & 1) * 64 + lg * 16) ^ (((l15 >> 1) & 7) << 4)));
        #pragma unroll
        for (int ot = 0; ot < 16; ++ot) {
            int o = ot * 16 + l15;
            bf16x8 bW2 = *(const bf16x8*)(sm + DBUF_OFF + 16384 +
                          (((o >> 1) * 128 + (o & 1) * 64 + lg * 16) ^ (((o >> 1) & 7) << 4)));
            Y[ot] = __builtin_amdgcn_mfma_f32_16x16x32_bf16(ah, bW2, Y[ot], 0, 0, 0);
        }
        __builtin_amdgcn_s_setprio(0);

        asm volatile("s_waitcnt lgkmcnt(0)" ::: "memory");
        __builtin_amdgcn_s_barrier();          // all waves done reading image p
        if (p < 31) {
            const char* src = wimg + (size_t)(p + 1) * 32768;
            #pragma unroll
            for (int i = 0; i < 8; ++i)
                gl_lds16(src + i * 4096 + t * 16, sm + DBUF_OFF + i * 4096 + t * 16);
        }
    }

    // ---- softmax over k (k = lg*4+r; registers + shfl) ----
    #pragma unroll
    for (int ot = 0; ot < 16; ++ot) {
        float mx = fmaxf(fmaxf(Y[ot][0], Y[ot][1]), fmaxf(Y[ot][2], Y[ot][3]));
        mx = fmaxf(mx, __shfl_xor(mx, 16));
        mx = fmaxf(mx, __shfl_xor(mx, 32));
        float e0 = expf(Y[ot][0] - mx), e1 = expf(Y[ot][1] - mx);
        float e2 = expf(Y[ot][2] - mx), e3 = expf(Y[ot][3] - mx);
        float s = e0 + e1 + e2 + e3;
        s += __shfl_xor(s, 16);
        s += __shfl_xor(s, 32);
        float inv = 1.f / s;
        Y[ot][0] = e0 * inv; Y[ot][1] = e1 * inv;
        Y[ot][2] = e2 * inv; Y[ot][3] = e3 * inv;
    }

    // ---- values -> vB regs via 4 slices; then v GEMM + agg ----
    bf16x8 vB[4];
    #pragma unroll 1
    for (int s = 0; s < 4; ++s) {
        const float* vb = values + ((size_t)b * 128 * NN + n) * 16 + kq * 4;
        #pragma unroll
        for (int h = 0; h < 2; ++h) {
            int c = s * 32 + h * 16 + cL;
            float4 v = *(const float4*)(vb + (size_t)c * NN * 16);
            int cl = h * 16 + cL;
            #pragma unroll
            for (int j = 0; j < 4; ++j) {
                int m = kq * 4 + j;
                float fj = (j == 0) ? v.x : (j == 1) ? v.y : (j == 2) ? v.z : v.w;
                *(unsigned short*)(scw + (((m >> 1) * 128 + (m & 1) * 64 + cl * 2) ^ (((m >> 1) & 7) << 4))) = f2bf(fj);
            }
        }
        vB[s] = *(const bf16x8*)(scw + (((l15 >> 1) * 128 + (l15 & 1) * 64 + lg * 16) ^ (((l15 >> 1) & 7) << 4)));
    }

    float aggv[16];
    #pragma unroll 4
    for (int ot = 0; ot < 16; ++ot) {
        int o = ot * 16 + l15;
        f32x4 va = zf;
        #pragma unroll
        for (int s = 0; s < 4; ++s) {
            bf16x8 bWv = *(const bf16x8*)(wvp + o * 128 + s * 32 + lg * 8);
            va = __builtin_amdgcn_mfma_f32_16x16x32_bf16(vB[s], bWv, va, 0, 0, 0);
        }
        float bvo = bv[o];
        float s = Y[ot][0] * (va[0] + bvo);
        s = fmaf(Y[ot][1], va[1] + bvo, s);
        s = fmaf(Y[ot][2], va[2] + bvo, s);
        s = fmaf(Y[ot][3], va[3] + bvo, s);
        s += __shfl_xor(s, 16);
        s += __shfl_xor(s, 32);
        aggv[ot] = s + bf2f(*(const unsigned short*)(pew + 512 + o * 2));
    }

    __syncthreads();
    // ---- agg hand-off: agg[16rows][256o] bf16 aliasing (pew+b1l) 8KB; row w = this n ----
    if (lg == 0) {
        #pragma unroll
        for (int ot = 0; ot < 16; ++ot) {
            int o = ot * 16 + l15;
            *(unsigned short*)(sm + PE_OFF + ((w * 512 + o * 2) ^ ((w & 7) << 4))) = f2bf(aggv[ot]);
        }
    }
    __syncthreads();

    // ---- We GEMM: wave owns 64 oo; A rows l15 (4 real n, rest garbage -> discarded) ----
    bf16x8 aa[8];
    #pragma unroll
    for (int kt = 0; kt < 8; ++kt)
        aa[kt] = *(const bf16x8*)(sm + PE_OFF + ((l15 * 512 + kt * 64 + lg * 16) ^ ((l15 & 7) << 4)));
    #pragma unroll
    for (int ot = 0; ot < 4; ++ot) {
        int oo = w * 64 + ot * 16 + l15;
        f32x4 acc = zf;
        #pragma unroll
        for (int kt = 0; kt < 8; ++kt) {
            bf16x8 bWe = *(const bf16x8*)(wep + oo * 256 + kt * 32 + lg * 8);
            acc = __builtin_amdgcn_mfma_f32_16x16x32_bf16(aa[kt], bWe, acc, 0, 0, 0);
        }
        if (lg == 0) {   // C rows lg*4+r = n0+r, valid rows 0..3
            float bev = be[oo];
            float4 vv;
            vv.x = acc[0] + bev; vv.y = acc[1] + bev;
            vv.z = acc[2] + bev; vv.w = acc[3] + bev;
            *(float4*)(outp + ((size_t)(b * 256 + oo)) * NN + n0) = vv;
        }
    }
}

extern "C" void kernel_launch(void* const* d_in, const int* in_sizes, int n_in,
                              void* d_out, int out_size, void* d_ws, size_t ws_size,
                              hipStream_t stream) {
    const float* key    = (const float*)d_in[0];
    const float* values = (const float*)d_in[1];
    const float* pos    = (const float*)d_in[2];
    const float* Wk     = (const float*)d_in[3];
    const float* bk     = (const float*)d_in[4];
    const float* Wq     = (const float*)d_in[5];
    const float* bq     = (const float*)d_in[6];
    const float* Wv     = (const float*)d_in[7];
    const float* bv     = (const float*)d_in[8];
    const float* Wp1    = (const float*)d_in[9];
    const float* bp1    = (const float*)d_in[10];
    const float* pg     = (const float*)d_in[11];
    const float* pb     = (const float*)d_in[12];
    const float* pm     = (const float*)d_in[13];
    const float* pv     = (const float*)d_in[14];
    const float* Wp2    = (const float*)d_in[15];
    const float* bp2    = (const float*)d_in[16];
    const float* Wa1    = (const float*)d_in[17];
    const float* ba1    = (const float*)d_in[18];
    const float* ag     = (const float*)d_in[19];
    const float* ab     = (const float*)d_in[20];
    const float* am     = (const float*)d_in[21];
    const float* av     = (const float*)d_in[22];
    const float* Wa2    = (const float*)d_in[23];
    const float* We     = (const float*)d_in[25];
    const float* be     = (const float*)d_in[26];
    (void)in_sizes; (void)n_in; (void)out_size; (void)ws_size;

    char* ws = (char*)d_ws;

    hipLaunchKernelGGL(prep_sc, dim3(5), dim3(256), 0, stream,
                       ag, ab, am, av, ba1, Wp1, Wq, bq, bp1, pg, pb, pm, pv, ws);
    hipLaunchKernelGGL(prep_cvt, dim3(640), dim3(256), 0, stream,
                       Wk, Wv, We, Wa1, Wa2, ws);
    hipLaunchKernelGGL(pt_main, dim3(2048), dim3(256), 0, stream,
                       key, values, pos, Wq, bq, bk, bv, Wp2, bp2, be,
                       (const char*)ws, (float*)d_out);
}